// Round 9
// baseline (498.036 us; speedup 1.0000x reference)
//
#include <hip/hip_runtime.h>

#define NN 50000
#define NE 800000
#define ND 64
#define ED 32
#define HID 64
#define NL 2
#define IN_MSG 96   // ND + ED
#define IN_UPD 128  // ND + HID
#define TWO_N (2 * NN)

#define W1_LD 104   // ushort stride for W1^T rows (96+8), 208B
#define H_LD 72     // ushort stride for h rows (64+8), 144B
#define MSG_LD 72   // ushort stride for msg staging rows, 144B
#define UPD_LD 136  // ushort stride for node comb rows (128+8), 272B

#define NBLK 768            // 3 blocks/CU x 256 CUs
#define WPB 4
#define TOTW (NBLK * WPB)   // 3072 waves
#define NGRP (NE / 32)      // 25000 groups of 32 edges
#define NB_SCAN 391         // ceil(2*NN/256)

typedef __attribute__((ext_vector_type(8))) short short8;  // 8 bf16 = 4 VGPR
typedef __attribute__((ext_vector_type(4))) float f32x4;
typedef __attribute__((ext_vector_type(2))) unsigned int u32x2;

__device__ inline ushort bf16r(float f) {  // fp32 -> bf16, RNE
    union { float f; unsigned u; } x; x.f = f;
    return (ushort)((x.u + 0x7FFFu + ((x.u >> 16) & 1u)) >> 16);
}
__device__ inline float b2f(unsigned u) {
    union { unsigned u; float f; } x; x.u = u << 16; return x.f;
}
__device__ inline float4 ntl_f4(const float4* p) {   // nontemporal float4 load
    const f32x4 v = __builtin_nontemporal_load(reinterpret_cast<const f32x4*>(p));
    return make_float4(v[0], v[1], v[2], v[3]);
}
__device__ inline short8 pk8(float4 a, float4 b) {
    short8 r;
    r[0] = (short)bf16r(a.x); r[1] = (short)bf16r(a.y);
    r[2] = (short)bf16r(a.z); r[3] = (short)bf16r(a.w);
    r[4] = (short)bf16r(b.x); r[5] = (short)bf16r(b.y);
    r[6] = (short)bf16r(b.z); r[7] = (short)bf16r(b.w);
    return r;
}
__device__ inline uint2 pack4(float4 v) {
    return make_uint2((unsigned)bf16r(v.x) | ((unsigned)bf16r(v.y) << 16),
                      (unsigned)bf16r(v.z) | ((unsigned)bf16r(v.w) << 16));
}

// ============================ CSR build (src + dst) =========================
// cnt layout: [0,NN) = src counts, [NN,2NN) = dst counts.
__global__ __launch_bounds__(256) void hist_kernel(const int* __restrict__ src,
                                                   const int* __restrict__ dst,
                                                   int* __restrict__ cnt)
{
    const int i = blockIdx.x * 256 + threadIdx.x;   // grid exact
    atomicAdd(&cnt[src[i]], 1);
    atomicAdd(&cnt[NN + dst[i]], 1);
}

// per-block exclusive scan of cnt[0..2NN) -> tmp in off slots ; totals -> bsum
__global__ __launch_bounds__(256) void scanA_kernel(const int* __restrict__ cnt,
                                                    int* __restrict__ scantmp,
                                                    int* __restrict__ bsum)
{
    __shared__ int buf[256];
    const int t = threadIdx.x;
    const int i = blockIdx.x * 256 + t;
    const int v = (i < TWO_N) ? cnt[i] : 0;
    buf[t] = v;
    __syncthreads();
    #pragma unroll
    for (int d = 1; d < 256; d <<= 1) {
        const int x = (t >= d) ? buf[t - d] : 0;
        __syncthreads();
        buf[t] += x;
        __syncthreads();
    }
    if (i < TWO_N) scantmp[i] = buf[t] - v;   // exclusive within block
    if (t == 255) bsum[blockIdx.x] = buf[255];
}

// inclusive scan of the 391 block sums (in place), 512 threads
__global__ __launch_bounds__(512) void scanB_kernel(int* __restrict__ bsum)
{
    __shared__ int buf[512];
    const int t = threadIdx.x;
    buf[t] = (t < NB_SCAN) ? bsum[t] : 0;
    __syncthreads();
    #pragma unroll
    for (int d = 1; d < 512; d <<= 1) {
        const int x = (t >= d) ? buf[t - d] : 0;
        __syncthreads();
        buf[t] += x;
        __syncthreads();
    }
    if (t < NB_SCAN) bsum[t] = buf[t];
}

// finalize: offS[i] (absolute), offD[i] (relative to dst base), cursor copies.
// off layout: off[0..NN] = src CSR (off[NN]=NE), off[NN+1 .. 2NN+1] = dst CSR.
__global__ __launch_bounds__(256) void scanC_kernel(const int* __restrict__ bsum,
                                                    const int* __restrict__ scantmp,
                                                    int* __restrict__ off,
                                                    int* __restrict__ cursor)
{
    const int b = blockIdx.x;
    const int i = b * 256 + threadIdx.x;
    const int boff = (b > 0) ? bsum[b - 1] : 0;
    if (i < TWO_N) {
        const int v = scantmp[i] + boff;
        if (i < NN) {                 // src half: absolute positions
            off[i] = v;
            cursor[i] = v;
        } else {                      // dst half: relative to NE
            off[i + 1] = v - NE;
            cursor[i] = v - NE;
        }
    }
    if (i == 0) { off[NN] = NE; off[TWO_N + 1] = NE; }
}

// scatter edge ids into src-sorted order; also emit the sorted src values
__global__ __launch_bounds__(256) void fill_src_kernel(const int* __restrict__ src,
                                                       int* __restrict__ cursor,
                                                       int* __restrict__ perm_src,
                                                       int* __restrict__ src_sorted)
{
    const int i = blockIdx.x * 256 + threadIdx.x;   // grid exact
    const int s = src[i];
    const int pos = atomicAdd(&cursor[s], 1);
    perm_src[pos] = i;
    src_sorted[pos] = s;
}

// dst CSR entries are src-sorted POSITIONS (so gather reads msgbuf[p])
__global__ __launch_bounds__(256) void fill_dst_kernel(const int* __restrict__ dst,
                                                       const int* __restrict__ perm_src,
                                                       int* __restrict__ cursor,
                                                       int* __restrict__ perm_dst)
{
    const int p = blockIdx.x * 256 + threadIdx.x;   // grid exact
    const int e = perm_src[p];
    const int d = dst[e];
    const int pos = atomicAdd(&cursor[NN + d], 1);
    perm_dst[pos] = p;
}

// ======================= edge message MLP (MFMA) ============================
// CSR=1: process edges in src-sorted order (nf locality); ef via perm_src;
//        nt-write bf16 messages to msgbuf at sorted position (coalesced).
// CSR=0: fallback — original order, direct C-frag atomics into agg/deg.
template <int CSR>
__global__ __launch_bounds__(256, 3)
void msg_kernel(const float* __restrict__ nf,
                const float* __restrict__ ef,
                const float* __restrict__ w1,
                const float* __restrict__ b1,
                const float* __restrict__ w2,
                const float* __restrict__ b2,
                const int* __restrict__ src,
                const int* __restrict__ dst,
                const int* __restrict__ psrc,   // perm_src (positions -> edge id)
                const int* __restrict__ ssrt,   // src_sorted
                ushort* __restrict__ msgbuf,
                float* __restrict__ agg,
                float* __restrict__ deg)
{
    __shared__ __align__(16) ushort sW1t[NL][64][W1_LD];   // 26,624 B
    __shared__ __align__(16) ushort sH[WPB][16][H_LD];     //  9,216 B
    __shared__ __align__(16) ushort sMsg[WPB][32][MSG_LD]; // 18,432 B => 54,272 B

    const int tid = threadIdx.x;
    const int w  = tid >> 6;
    const int l  = tid & 63;
    const int lr = l & 15;
    const int lg = l >> 4;

    // ---- one-time stage: W1^T (padded) ----
    {
        const int k16 = tid >> 4, n0 = (tid & 15) * 4;
        #pragma unroll
        for (int lay = 0; lay < NL; ++lay)
            #pragma unroll
            for (int it = 0; it < 6; ++it) {
                const int k = k16 + 16 * it;   // 0..95
                const float4 v = *reinterpret_cast<const float4*>(
                    w1 + ((size_t)lay * IN_MSG + k) * HID + n0);
                sW1t[lay][n0 + 0][k] = bf16r(v.x);
                sW1t[lay][n0 + 1][k] = bf16r(v.y);
                sW1t[lay][n0 + 2][k] = bf16r(v.z);
                sW1t[lay][n0 + 3][k] = bf16r(v.w);
            }
    }
    // ---- W2 B-fragments in registers (both layers) ----
    short8 w2f[NL][4][2];
    #pragma unroll
    for (int lay = 0; lay < NL; ++lay)
        #pragma unroll
        for (int nt = 0; nt < 4; ++nt)
            #pragma unroll
            for (int ks = 0; ks < 2; ++ks) {
                short8 t;
                #pragma unroll
                for (int j = 0; j < 8; ++j)
                    t[j] = (short)bf16r(
                        w2[((size_t)lay * HID + ks * 32 + 8 * lg + j) * HID + nt * 16 + lr]);
                w2f[lay][nt][ks] = t;
            }
    // ---- biases in registers ----
    float bias1[NL][4], bias2s[4];
    #pragma unroll
    for (int lay = 0; lay < NL; ++lay)
        #pragma unroll
        for (int nt = 0; nt < 4; ++nt)
            bias1[lay][nt] = b1[lay * HID + nt * 16 + lr];
    #pragma unroll
    for (int nt = 0; nt < 4; ++nt)
        bias2s[nt] = b2[nt * 16 + lr] + b2[HID + nt * 16 + lr];
    __syncthreads();

    const float4* nfr = reinterpret_cast<const float4*>(nf);  // 16 float4 / row
    const float4* efr = reinterpret_cast<const float4*>(ef);  //  8 float4 / row

    // ---- prologue: indices for generation 0 and 1 ----
    int g = blockIdx.x * WPB + w;
    int ssv = 0, pev = 0, dstv = 0;   // current: src value, edge id, dst (fallback)
    int ssn = 0, pen = 0, dstn = 0;   // next
    if (l < 32) {
        if (CSR) { pev = psrc[(size_t)g * 32 + l]; ssv = ssrt[(size_t)g * 32 + l]; }
        else     { ssv = src[(size_t)g * 32 + l];  dstv = dst[(size_t)g * 32 + l]; }
    }
    {
        const int gn = g + TOTW;
        if (gn < NGRP && l < 32) {
            if (CSR) { pen = psrc[(size_t)gn * 32 + l]; ssn = ssrt[(size_t)gn * 32 + l]; }
            else     { ssn = src[(size_t)gn * 32 + l];  dstn = dst[(size_t)gn * 32 + l]; }
        }
    }
    float4 nfv[2][4], efv[2][2];
    #pragma unroll
    for (int mt = 0; mt < 2; ++mt) {
        const int s = __shfl(ssv, mt * 16 + lr);
        const float4* p = nfr + (size_t)s * 16;
        nfv[mt][0] = p[2 * lg];     nfv[mt][1] = p[2 * lg + 1];
        nfv[mt][2] = p[8 + 2 * lg]; nfv[mt][3] = p[9 + 2 * lg];
        const int e = CSR ? __shfl(pev, mt * 16 + lr) : (g * 32 + mt * 16 + lr);
        const float4* q = efr + (size_t)e * 8;
        efv[mt][0] = ntl_f4(q + 2 * lg);
        efv[mt][1] = ntl_f4(q + 2 * lg + 1);
    }

    #pragma unroll 1
    while (g < NGRP) {
        const int gn  = g + TOTW;
        const int gnn = g + 2 * TOTW;
        const bool more = (gn < NGRP);

        short8 cmbA[2][3];
        #pragma unroll
        for (int mt = 0; mt < 2; ++mt) {
            cmbA[mt][0] = pk8(nfv[mt][0], nfv[mt][1]);
            cmbA[mt][1] = pk8(nfv[mt][2], nfv[mt][3]);
            cmbA[mt][2] = pk8(efv[mt][0], efv[mt][1]);
        }

        int ssn2 = 0, pen2 = 0, dstn2 = 0;
        if (gnn < NGRP && l < 32) {
            if (CSR) { pen2 = psrc[(size_t)gnn * 32 + l]; ssn2 = ssrt[(size_t)gnn * 32 + l]; }
            else     { ssn2 = src[(size_t)gnn * 32 + l];  dstn2 = dst[(size_t)gnn * 32 + l]; }
        }
        float4 nfn[2][4], efn[2][2];
        if (more) {
            #pragma unroll
            for (int mt = 0; mt < 2; ++mt) {
                const int e = CSR ? __shfl(pen, mt * 16 + lr) : (gn * 32 + mt * 16 + lr);
                const float4* q = efr + (size_t)e * 8;
                efn[mt][0] = ntl_f4(q + 2 * lg);
                efn[mt][1] = ntl_f4(q + 2 * lg + 1);
            }
        }

        f32x4 msg[2][4];
        #pragma unroll
        for (int nt = 0; nt < 4; ++nt) {
            const float v = bias2s[nt];
            msg[0][nt] = (f32x4){v, v, v, v};
            msg[1][nt] = (f32x4){v, v, v, v};
        }

        #pragma unroll
        for (int lay = 0; lay < NL; ++lay) {
            #pragma unroll
            for (int mt = 0; mt < 2; ++mt) {
                f32x4 acc[4];
                #pragma unroll
                for (int nt = 0; nt < 4; ++nt) {
                    const float bv = bias1[lay][nt];
                    acc[nt] = (f32x4){bv, bv, bv, bv};
                }
                __builtin_amdgcn_s_setprio(1);
                #pragma unroll
                for (int ks = 0; ks < 3; ++ks)
                    #pragma unroll
                    for (int nt = 0; nt < 4; ++nt) {
                        const short8 B = *reinterpret_cast<const short8*>(
                            &sW1t[lay][nt * 16 + lr][ks * 32 + 8 * lg]);
                        acc[nt] = __builtin_amdgcn_mfma_f32_16x16x32_bf16(
                            cmbA[mt][ks], B, acc[nt], 0, 0, 0);
                    }
                __builtin_amdgcn_s_setprio(0);
                #pragma unroll
                for (int nt = 0; nt < 4; ++nt)
                    #pragma unroll
                    for (int r = 0; r < 4; ++r)
                        sH[w][4 * lg + r][nt * 16 + lr] = bf16r(fmaxf(acc[nt][r], 0.0f));
                const short8 h0 = *reinterpret_cast<const short8*>(&sH[w][lr][ 0 + 8 * lg]);
                const short8 h1 = *reinterpret_cast<const short8*>(&sH[w][lr][32 + 8 * lg]);
                __builtin_amdgcn_s_setprio(1);
                #pragma unroll
                for (int nt = 0; nt < 4; ++nt) {
                    msg[mt][nt] = __builtin_amdgcn_mfma_f32_16x16x32_bf16(h0, w2f[lay][nt][0], msg[mt][nt], 0, 0, 0);
                    msg[mt][nt] = __builtin_amdgcn_mfma_f32_16x16x32_bf16(h1, w2f[lay][nt][1], msg[mt][nt], 0, 0, 0);
                }
                __builtin_amdgcn_s_setprio(0);
            }
            if (lay == 0 && more) {
                #pragma unroll
                for (int mt = 0; mt < 2; ++mt) {
                    const int s = __shfl(ssn, mt * 16 + lr);
                    const float4* p = nfr + (size_t)s * 16;
                    nfn[mt][0] = p[2 * lg];     nfn[mt][1] = p[2 * lg + 1];
                    nfn[mt][2] = p[8 + 2 * lg]; nfn[mt][3] = p[9 + 2 * lg];
                }
            }
        }

        if (CSR) {
            // ---- flush: LDS transpose -> nt-store coalesced bf16 rows at position ----
            #pragma unroll
            for (int mt = 0; mt < 2; ++mt)
                #pragma unroll
                for (int nt = 0; nt < 4; ++nt)
                    #pragma unroll
                    for (int r = 0; r < 4; ++r)
                        sMsg[w][mt * 16 + 4 * lg + r][nt * 16 + lr] = bf16r(msg[mt][nt][r]);
            #pragma unroll
            for (int it = 0; it < 4; ++it) {
                const int row = (l >> 3) + 8 * it;
                const int c8  = l & 7;
                const short8 v = *reinterpret_cast<const short8*>(&sMsg[w][row][c8 * 8]);
                __builtin_nontemporal_store(v, reinterpret_cast<short8*>(
                    msgbuf + ((size_t)(g * 32 + row)) * 64 + c8 * 8));
            }
        } else {
            #pragma unroll
            for (int mt = 0; mt < 2; ++mt)
                #pragma unroll
                for (int r = 0; r < 4; ++r) {
                    const int drow = __shfl(dstv, mt * 16 + 4 * lg + r);
                    float* rowp = agg + (size_t)drow * HID;
                    #pragma unroll
                    for (int nt = 0; nt < 4; ++nt)
                        atomicAdd(rowp + nt * 16 + lr, msg[mt][nt][r]);
                }
            if (l < 32) atomicAdd(&deg[dstv], 1.0f);
        }

        ssv = ssn; pev = pen; dstv = dstn;
        ssn = ssn2; pen = pen2; dstn = dstn2;
        #pragma unroll
        for (int mt = 0; mt < 2; ++mt) {
            #pragma unroll
            for (int i = 0; i < 4; ++i) nfv[mt][i] = nfn[mt][i];
            efv[mt][0] = efn[mt][0]; efv[mt][1] = efn[mt][1];
        }
        g = gn;
    }
}

// ================== CSR gather: one node per quarter-wave ===================
// perm_dst entries are src-sorted POSITIONS; msgbuf indexed by position.
// Writes NORMALIZED aggregate rows into aggout (= d_out, block-disjoint rows).
__global__ __launch_bounds__(256)
void gather_kernel(const ushort* __restrict__ msgbuf,
                   const int* __restrict__ perm,
                   const int* __restrict__ off,
                   float* __restrict__ aggout)
{
    const int tid  = threadIdx.x;
    const int node = blockIdx.x * 16 + (tid >> 4);   // 3125*16 = 50000 exact
    const int ql   = tid & 15;
    const int qb   = ((tid >> 4) & 3) * 16;          // quarter's base lane in wave

    const int o0 = off[node];
    const int o1 = off[node + 1];
    float a0 = 0.f, a1 = 0.f, a2 = 0.f, a3 = 0.f;

    #pragma unroll 1
    for (int base = o0; base < o1; base += 16) {
        const int rem = o1 - base;
        int pe = 0;
        if (ql < rem) pe = perm[base + ql];
        if (rem >= 16) {
            #pragma unroll
            for (int j = 0; j < 16; ++j) {
                const int e = __shfl(pe, qb + j);
                const u32x2 mv = __builtin_nontemporal_load(
                    reinterpret_cast<const u32x2*>(msgbuf + (size_t)e * 64 + ql * 4));
                a0 += b2f(mv.x & 0xffffu); a1 += b2f(mv.x >> 16);
                a2 += b2f(mv.y & 0xffffu); a3 += b2f(mv.y >> 16);
            }
        } else {
            #pragma unroll 1
            for (int j = 0; j < rem; ++j) {
                const int e = __shfl(pe, qb + j);
                const u32x2 mv = __builtin_nontemporal_load(
                    reinterpret_cast<const u32x2*>(msgbuf + (size_t)e * 64 + ql * 4));
                a0 += b2f(mv.x & 0xffffu); a1 += b2f(mv.x >> 16);
                a2 += b2f(mv.y & 0xffffu); a3 += b2f(mv.y >> 16);
            }
        }
    }
    const float invd = 1.0f / ((float)(o1 - o0) + 1e-8f);
    const float4 r = make_float4(a0 * invd, a1 * invd, a2 * invd, a3 * invd);
    *reinterpret_cast<float4*>(aggout + (size_t)node * HID + ql * 4) = r;
}

// ============ node update from normalized agg (agg lives in d_out) ==========
__global__ __launch_bounds__(256, 2)
void node_update_agg_kernel(const float* __restrict__ nf,
                            const float* __restrict__ aggin,   // == out
                            const float* __restrict__ uw1,
                            const float* __restrict__ ub1,
                            const float* __restrict__ uw2,
                            const float* __restrict__ ub2,
                            float* __restrict__ out)
{
    __shared__ __align__(16) ushort sAct[WPB][32][UPD_LD];
    __shared__ __align__(16) ushort sW1t[64][UPD_LD];
    __shared__ __align__(16) ushort sW2t[64][H_LD];
    __shared__ float sUB1[64], sUB2[64];

    const int tid = threadIdx.x;
    const int w  = tid >> 6;
    const int l  = tid & 63;
    const int lr = l & 15;
    const int lg = l >> 4;

    {   // weight stage
        const int k16 = tid >> 4, n0 = (tid & 15) * 4;
        #pragma unroll
        for (int it = 0; it < 8; ++it) {
            const int k = k16 + 16 * it;
            const float4 v = *reinterpret_cast<const float4*>(uw1 + (size_t)k * HID + n0);
            sW1t[n0 + 0][k] = bf16r(v.x);
            sW1t[n0 + 1][k] = bf16r(v.y);
            sW1t[n0 + 2][k] = bf16r(v.z);
            sW1t[n0 + 3][k] = bf16r(v.w);
        }
        #pragma unroll
        for (int it = 0; it < 4; ++it) {
            const int k = k16 + 16 * it;
            const float4 v = *reinterpret_cast<const float4*>(uw2 + (size_t)k * ND + n0);
            sW2t[n0 + 0][k] = bf16r(v.x);
            sW2t[n0 + 1][k] = bf16r(v.y);
            sW2t[n0 + 2][k] = bf16r(v.z);
            sW2t[n0 + 3][k] = bf16r(v.w);
        }
        if (tid < 64) { sUB1[tid] = ub1[tid]; sUB2[tid] = ub2[tid]; }
    }

    const int nbase = blockIdx.x * 128 + w * 32;

    #pragma unroll
    for (int it = 0; it < 8; ++it) {
        const int row = lg + 4 * it;
        const int n = min(nbase + row, NN - 1);
        const float4 v = reinterpret_cast<const float4*>(nf + (size_t)n * ND)[lr];
        *reinterpret_cast<uint2*>(&sAct[w][row][lr * 4]) = pack4(v);
    }
    #pragma unroll
    for (int it = 0; it < 8; ++it) {
        const int row = lg + 4 * it;
        const int n = min(nbase + row, NN - 1);
        const float4 v = reinterpret_cast<const float4*>(aggin + (size_t)n * HID)[lr];
        *reinterpret_cast<uint2*>(&sAct[w][row][ND + lr * 4]) = pack4(v);
    }
    __syncthreads();

    short8 A[2][4];
    #pragma unroll
    for (int mt = 0; mt < 2; ++mt)
        #pragma unroll
        for (int ks = 0; ks < 4; ++ks)
            A[mt][ks] = *reinterpret_cast<const short8*>(&sAct[w][mt * 16 + lr][ks * 32 + 8 * lg]);
    #pragma unroll
    for (int nt = 0; nt < 4; ++nt) {
        const int cB = nt * 16 + lr;
        short8 B[4];
        #pragma unroll
        for (int ks = 0; ks < 4; ++ks)
            B[ks] = *reinterpret_cast<const short8*>(&sW1t[cB][ks * 32 + 8 * lg]);
        const float bv = sUB1[cB];
        #pragma unroll
        for (int mt = 0; mt < 2; ++mt) {
            f32x4 acc = (f32x4){bv, bv, bv, bv};
            #pragma unroll
            for (int ks = 0; ks < 4; ++ks)
                acc = __builtin_amdgcn_mfma_f32_16x16x32_bf16(A[mt][ks], B[ks], acc, 0, 0, 0);
            const int rH = mt * 16 + 4 * lg;
            #pragma unroll
            for (int r = 0; r < 4; ++r)
                sAct[w][rH + r][cB] = bf16r(fmaxf(acc[r], 0.0f));
        }
    }

    f32x4 o[2][4];
    #pragma unroll
    for (int nt = 0; nt < 4; ++nt) {
        const float v = sUB2[nt * 16 + lr];
        o[0][nt] = (f32x4){v, v, v, v};
        o[1][nt] = (f32x4){v, v, v, v};
    }
    #pragma unroll
    for (int mt = 0; mt < 2; ++mt) {
        const short8 A0 = *reinterpret_cast<const short8*>(&sAct[w][mt * 16 + lr][ 0 + 8 * lg]);
        const short8 A1 = *reinterpret_cast<const short8*>(&sAct[w][mt * 16 + lr][32 + 8 * lg]);
        #pragma unroll
        for (int nt = 0; nt < 4; ++nt) {
            const int cB = nt * 16 + lr;
            const short8 B0 = *reinterpret_cast<const short8*>(&sW2t[cB][ 0 + 8 * lg]);
            const short8 B1 = *reinterpret_cast<const short8*>(&sW2t[cB][32 + 8 * lg]);
            o[mt][nt] = __builtin_amdgcn_mfma_f32_16x16x32_bf16(A0, B0, o[mt][nt], 0, 0, 0);
            o[mt][nt] = __builtin_amdgcn_mfma_f32_16x16x32_bf16(A1, B1, o[mt][nt], 0, 0, 0);
        }
    }

    #pragma unroll
    for (int mt = 0; mt < 2; ++mt)
        #pragma unroll
        for (int r = 0; r < 4; ++r) {
            const int n = nbase + mt * 16 + 4 * lg + r;
            if (n < NN) {
                float* rowp = out + (size_t)n * ND;
                #pragma unroll
                for (int nt = 0; nt < 4; ++nt)
                    rowp[nt * 16 + lr] = o[mt][nt][r];
            }
        }
}

// ============== fallback node update (atomic-agg path, round-5) =============
__global__ __launch_bounds__(256, 2)
void node_update_kernel(const float* __restrict__ nf,
                        const float* __restrict__ agg,
                        const float* __restrict__ deg,
                        const float* __restrict__ uw1,
                        const float* __restrict__ ub1,
                        const float* __restrict__ uw2,
                        const float* __restrict__ ub2,
                        float* __restrict__ out)
{
    __shared__ __align__(16) ushort sAct[WPB][32][UPD_LD];
    __shared__ __align__(16) ushort sW1t[64][UPD_LD];
    __shared__ __align__(16) ushort sW2t[64][H_LD];
    __shared__ float sUB1[64], sUB2[64];

    const int tid = threadIdx.x;
    const int w  = tid >> 6;
    const int l  = tid & 63;
    const int lr = l & 15;
    const int lg = l >> 4;

    {
        const int k16 = tid >> 4, n0 = (tid & 15) * 4;
        #pragma unroll
        for (int it = 0; it < 8; ++it) {
            const int k = k16 + 16 * it;
            const float4 v = *reinterpret_cast<const float4*>(uw1 + (size_t)k * HID + n0);
            sW1t[n0 + 0][k] = bf16r(v.x);
            sW1t[n0 + 1][k] = bf16r(v.y);
            sW1t[n0 + 2][k] = bf16r(v.z);
            sW1t[n0 + 3][k] = bf16r(v.w);
        }
        #pragma unroll
        for (int it = 0; it < 4; ++it) {
            const int k = k16 + 16 * it;
            const float4 v = *reinterpret_cast<const float4*>(uw2 + (size_t)k * ND + n0);
            sW2t[n0 + 0][k] = bf16r(v.x);
            sW2t[n0 + 1][k] = bf16r(v.y);
            sW2t[n0 + 2][k] = bf16r(v.z);
            sW2t[n0 + 3][k] = bf16r(v.w);
        }
        if (tid < 64) { sUB1[tid] = ub1[tid]; sUB2[tid] = ub2[tid]; }
    }

    const int nbase = blockIdx.x * 128 + w * 32;
    float invv = 0.0f;
    if (l < 32) invv = 1.0f / (deg[min(nbase + l, NN - 1)] + 1e-8f);

    #pragma unroll
    for (int it = 0; it < 8; ++it) {
        const int row = lg + 4 * it;
        const int n = min(nbase + row, NN - 1);
        const float4 v = reinterpret_cast<const float4*>(nf + (size_t)n * ND)[lr];
        *reinterpret_cast<uint2*>(&sAct[w][row][lr * 4]) = pack4(v);
    }
    #pragma unroll
    for (int it = 0; it < 8; ++it) {
        const int row = lg + 4 * it;
        const int n = min(nbase + row, NN - 1);
        const float iv = __shfl(invv, row);
        float4 v = reinterpret_cast<const float4*>(agg + (size_t)n * HID)[lr];
        v.x *= iv; v.y *= iv; v.z *= iv; v.w *= iv;
        *reinterpret_cast<uint2*>(&sAct[w][row][ND + lr * 4]) = pack4(v);
    }
    __syncthreads();

    short8 A[2][4];
    #pragma unroll
    for (int mt = 0; mt < 2; ++mt)
        #pragma unroll
        for (int ks = 0; ks < 4; ++ks)
            A[mt][ks] = *reinterpret_cast<const short8*>(&sAct[w][mt * 16 + lr][ks * 32 + 8 * lg]);
    #pragma unroll
    for (int nt = 0; nt < 4; ++nt) {
        const int cB = nt * 16 + lr;
        short8 B[4];
        #pragma unroll
        for (int ks = 0; ks < 4; ++ks)
            B[ks] = *reinterpret_cast<const short8*>(&sW1t[cB][ks * 32 + 8 * lg]);
        const float bv = sUB1[cB];
        #pragma unroll
        for (int mt = 0; mt < 2; ++mt) {
            f32x4 acc = (f32x4){bv, bv, bv, bv};
            #pragma unroll
            for (int ks = 0; ks < 4; ++ks)
                acc = __builtin_amdgcn_mfma_f32_16x16x32_bf16(A[mt][ks], B[ks], acc, 0, 0, 0);
            const int rH = mt * 16 + 4 * lg;
            #pragma unroll
            for (int r = 0; r < 4; ++r)
                sAct[w][rH + r][cB] = bf16r(fmaxf(acc[r], 0.0f));
        }
    }

    f32x4 o[2][4];
    #pragma unroll
    for (int nt = 0; nt < 4; ++nt) {
        const float v = sUB2[nt * 16 + lr];
        o[0][nt] = (f32x4){v, v, v, v};
        o[1][nt] = (f32x4){v, v, v, v};
    }
    #pragma unroll
    for (int mt = 0; mt < 2; ++mt) {
        const short8 A0 = *reinterpret_cast<const short8*>(&sAct[w][mt * 16 + lr][ 0 + 8 * lg]);
        const short8 A1 = *reinterpret_cast<const short8*>(&sAct[w][mt * 16 + lr][32 + 8 * lg]);
        #pragma unroll
        for (int nt = 0; nt < 4; ++nt) {
            const int cB = nt * 16 + lr;
            const short8 B0 = *reinterpret_cast<const short8*>(&sW2t[cB][ 0 + 8 * lg]);
            const short8 B1 = *reinterpret_cast<const short8*>(&sW2t[cB][32 + 8 * lg]);
            o[mt][nt] = __builtin_amdgcn_mfma_f32_16x16x32_bf16(A0, B0, o[mt][nt], 0, 0, 0);
            o[mt][nt] = __builtin_amdgcn_mfma_f32_16x16x32_bf16(A1, B1, o[mt][nt], 0, 0, 0);
        }
    }

    #pragma unroll
    for (int mt = 0; mt < 2; ++mt)
        #pragma unroll
        for (int r = 0; r < 4; ++r) {
            const int n = nbase + mt * 16 + 4 * lg + r;
            if (n < NN) {
                float* rowp = out + (size_t)n * ND;
                #pragma unroll
                for (int nt = 0; nt < 4; ++nt)
                    rowp[nt * 16 + lr] = o[mt][nt][r];
            }
        }
}

extern "C" void kernel_launch(void* const* d_in, const int* in_sizes, int n_in,
                              void* d_out, int out_size, void* d_ws, size_t ws_size,
                              hipStream_t stream)
{
    const float* nf  = (const float*)d_in[0];
    const float* ef  = (const float*)d_in[1];
    const float* w1  = (const float*)d_in[2];
    const float* b1  = (const float*)d_in[3];
    const float* w2  = (const float*)d_in[4];
    const float* b2  = (const float*)d_in[5];
    const float* uw1 = (const float*)d_in[6];
    const float* ub1 = (const float*)d_in[7];
    const float* uw2 = (const float*)d_in[8];
    const float* ub2 = (const float*)d_in[9];
    const int*   src = (const int*)d_in[10];
    const int*   dst = (const int*)d_in[11];
    float* out = (float*)d_out;

    // ws layout
    constexpr size_t MSGB  = (size_t)NE * 64 * 2;        // 102,400,000
    constexpr size_t PERMB = (size_t)NE * 4;             //   3,200,000 (perm_dst)
    constexpr size_t TMPB  = (size_t)TWO_N * 4;          //     400,000 (scantmp)
    constexpr size_t OFFB  = (size_t)(TWO_N + 2) * 4 + 8;//     400,016 (off, padded)
    constexpr size_t CNTB  = (size_t)TWO_N * 4;          //     400,000 (cnt/cursor)
    constexpr size_t BSUMB = 2048;                       // 391*4 padded
    constexpr size_t NEED  = MSGB + PERMB + TMPB + OFFB + CNTB + BSUMB;

    if (ws_size >= NEED) {
        char* wsc = (char*)d_ws;
        ushort* msgbuf  = (ushort*)wsc;
        int* perm_dst   = (int*)(wsc + MSGB);
        int* scantmp    = (int*)(wsc + MSGB + PERMB);
        int* off        = (int*)(wsc + MSGB + PERMB + TMPB);
        int* cnt        = (int*)(wsc + MSGB + PERMB + TMPB + OFFB);   // also cursor
        int* bsum       = (int*)(wsc + MSGB + PERMB + TMPB + OFFB + CNTB);
        // perm_src + src_sorted live in d_out (dead before gather overwrites it)
        int* perm_src   = (int*)d_out;          // [NE] = 3.2MB
        int* src_sorted = (int*)d_out + NE;     // [NE] = 3.2MB (12.8MB available)
        const int* offD = off + NN + 1;

        (void)hipMemsetAsync(cnt, 0, CNTB, stream);
        hist_kernel<<<NE / 256, 256, 0, stream>>>(src, dst, cnt);
        scanA_kernel<<<NB_SCAN, 256, 0, stream>>>(cnt, scantmp, bsum);
        scanB_kernel<<<1, 512, 0, stream>>>(bsum);
        scanC_kernel<<<NB_SCAN, 256, 0, stream>>>(bsum, scantmp, off, cnt);
        fill_src_kernel<<<NE / 256, 256, 0, stream>>>(src, cnt, perm_src, src_sorted);
        fill_dst_kernel<<<NE / 256, 256, 0, stream>>>(dst, perm_src, cnt, perm_dst);
        msg_kernel<1><<<NBLK, 256, 0, stream>>>(nf, ef, w1, b1, w2, b2, src, dst,
                                                perm_src, src_sorted,
                                                msgbuf, nullptr, nullptr);
        gather_kernel<<<NN / 16, 256, 0, stream>>>(msgbuf, perm_dst, offD, out);
        node_update_agg_kernel<<<(NN + 127) / 128, 256, 0, stream>>>(
            nf, out, uw1, ub1, uw2, ub2, out);
    } else {
        float* agg = (float*)d_ws;                    // [NN][HID]
        float* deg = agg + (size_t)NN * HID;          // [NN]
        (void)hipMemsetAsync(d_ws, 0, ((size_t)NN * HID + NN) * sizeof(float), stream);
        msg_kernel<0><<<NBLK, 256, 0, stream>>>(nf, ef, w1, b1, w2, b2, src, dst,
                                                nullptr, nullptr, nullptr, agg, deg);
        node_update_kernel<<<(NN + 127) / 128, 256, 0, stream>>>(nf, agg, deg,
                                                                 uw1, ub1, uw2, ub2, out);
    }
}

// Round 10
// 208.872 us; speedup vs baseline: 2.3844x; 2.3844x over previous
//
#include <hip/hip_runtime.h>

#define NN 50000
#define NE 800000
#define ND 64
#define ED 32
#define HID 64
#define NL 2
#define IN_MSG 96   // ND + ED
#define IN_UPD 128  // ND + HID

#define W1_LD 104   // ushort stride for W1^T rows (96+8), 208B
#define MSG_LD 72   // ushort stride for msg/h scratch rows, 144B
#define UPD_LD 136  // ushort stride for node comb rows (128+8), 272B

#define NBLK 512            // 2 blocks/CU x 256 CUs
#define WPB 4
#define TOTW (NBLK * WPB)   // 2048 waves
#define NGRP (NE / 32)      // 25000 groups of 32 edges
#define NB_SCAN 196         // ceil(NN/256)

typedef __attribute__((ext_vector_type(8))) short short8;  // 8 bf16 = 4 VGPR
typedef __attribute__((ext_vector_type(4))) float f32x4;

__device__ inline ushort bf16r(float f) {  // fp32 -> bf16, RNE
    union { float f; unsigned u; } x; x.f = f;
    return (ushort)((x.u + 0x7FFFu + ((x.u >> 16) & 1u)) >> 16);
}
__device__ inline float b2f(unsigned u) {
    union { unsigned u; float f; } x; x.u = u << 16; return x.f;
}
__device__ inline short8 pk8(float4 a, float4 b) {
    short8 r;
    r[0] = (short)bf16r(a.x); r[1] = (short)bf16r(a.y);
    r[2] = (short)bf16r(a.z); r[3] = (short)bf16r(a.w);
    r[4] = (short)bf16r(b.x); r[5] = (short)bf16r(b.y);
    r[6] = (short)bf16r(b.z); r[7] = (short)bf16r(b.w);
    return r;
}
__device__ inline uint2 pack4(float4 v) {
    return make_uint2((unsigned)bf16r(v.x) | ((unsigned)bf16r(v.y) << 16),
                      (unsigned)bf16r(v.z) | ((unsigned)bf16r(v.w) << 16));
}

// ============================ dst-CSR build =================================
__global__ __launch_bounds__(256) void hist_kernel(const int* __restrict__ dst,
                                                   int* __restrict__ cnt)
{
    const int i = blockIdx.x * 256 + threadIdx.x;   // grid exact
    atomicAdd(&cnt[dst[i]], 1);
}

__global__ __launch_bounds__(256) void scanA_kernel(const int* __restrict__ cnt,
                                                    int* __restrict__ off,
                                                    int* __restrict__ bsum)
{
    __shared__ int buf[256];
    const int t = threadIdx.x;
    const int i = blockIdx.x * 256 + t;
    const int v = (i < NN) ? cnt[i] : 0;
    buf[t] = v;
    __syncthreads();
    #pragma unroll
    for (int d = 1; d < 256; d <<= 1) {
        const int x = (t >= d) ? buf[t - d] : 0;
        __syncthreads();
        buf[t] += x;
        __syncthreads();
    }
    if (i < NN) off[i] = buf[t] - v;          // exclusive within block
    if (t == 255) bsum[blockIdx.x] = buf[255];
}

__global__ __launch_bounds__(256) void scanB_kernel(int* __restrict__ bsum)
{
    __shared__ int buf[256];
    const int t = threadIdx.x;
    buf[t] = (t < NB_SCAN) ? bsum[t] : 0;
    __syncthreads();
    #pragma unroll
    for (int d = 1; d < 256; d <<= 1) {
        const int x = (t >= d) ? buf[t - d] : 0;
        __syncthreads();
        buf[t] += x;
        __syncthreads();
    }
    if (t < NB_SCAN) bsum[t] = buf[t];
}

__global__ __launch_bounds__(256) void scanC_kernel(const int* __restrict__ bsum,
                                                    int* __restrict__ off,
                                                    int* __restrict__ cursor)
{
    const int b = blockIdx.x;
    const int i = b * 256 + threadIdx.x;
    const int boff = (b > 0) ? bsum[b - 1] : 0;
    if (i < NN) {
        const int e = off[i] + boff;
        off[i] = e;
        cursor[i] = e;
    }
    if (i == 0) off[NN] = NE;
}

// scatter into dst-sorted order: edge id, src value, dst value
__global__ __launch_bounds__(256) void fill_kernel(const int* __restrict__ src,
                                                   const int* __restrict__ dst,
                                                   int* __restrict__ cursor,
                                                   int* __restrict__ esort,
                                                   int* __restrict__ ssort,
                                                   int* __restrict__ dsort)
{
    const int i = blockIdx.x * 256 + threadIdx.x;   // grid exact
    const int d = dst[i];
    const int pos = atomicAdd(&cursor[d], 1);
    esort[pos] = i;
    ssort[pos] = src[i];
    dsort[pos] = d;
}

// ======================= edge message MLP (MFMA) ============================
// SORTED=1: edges in dst-sorted order; per-group LDS transpose + segmented
//           in-register reduction -> ~3 coalesced row-atomics per group.
// SORTED=0: fallback — original order, one atomic row per edge + deg.
template <int SORTED>
__global__ __launch_bounds__(256, 2)
void msg_kernel(const float* __restrict__ nf,
                const float* __restrict__ ef,
                const float* __restrict__ w1,
                const float* __restrict__ b1,
                const float* __restrict__ w2,
                const float* __restrict__ b2,
                const int* __restrict__ src,
                const int* __restrict__ dst,
                const int* __restrict__ esort,
                const int* __restrict__ ssort,
                const int* __restrict__ dsort,
                float* __restrict__ agg,
                float* __restrict__ deg)
{
    __shared__ __align__(16) ushort sW1t[NL][64][W1_LD];  // 26,624 B
    __shared__ __align__(16) ushort sW2t[NL][64][64];     // 16,384 B (XOR-swizzled)
    __shared__ __align__(16) ushort sMS[WPB][32][MSG_LD]; // 18,432 B => 61,440 B
    // sMS rows 0..15 double as the h buffer during GEMMs (wave-private).

    const int tid = threadIdx.x;
    const int w  = tid >> 6;
    const int l  = tid & 63;
    const int lr = l & 15;
    const int lg = l >> 4;

    // ---- one-time stage: W1^T (padded) + W2^T (swizzled) ----
    {
        const int k16 = tid >> 4, n0 = (tid & 15) * 4;
        #pragma unroll
        for (int lay = 0; lay < NL; ++lay) {
            #pragma unroll
            for (int it = 0; it < 6; ++it) {
                const int k = k16 + 16 * it;   // 0..95
                const float4 v = *reinterpret_cast<const float4*>(
                    w1 + ((size_t)lay * IN_MSG + k) * HID + n0);
                sW1t[lay][n0 + 0][k] = bf16r(v.x);
                sW1t[lay][n0 + 1][k] = bf16r(v.y);
                sW1t[lay][n0 + 2][k] = bf16r(v.z);
                sW1t[lay][n0 + 3][k] = bf16r(v.w);
            }
            #pragma unroll
            for (int it = 0; it < 4; ++it) {
                const int k = k16 + 16 * it;   // 0..63
                const float4 v = *reinterpret_cast<const float4*>(
                    w2 + ((size_t)lay * HID + k) * HID + n0);
                const ushort vals[4] = {bf16r(v.x), bf16r(v.y), bf16r(v.z), bf16r(v.w)};
                #pragma unroll
                for (int j = 0; j < 4; ++j) {
                    const int row = n0 + j;
                    const int colS = (((k >> 3) ^ (row & 7)) << 3) | (k & 7);
                    sW2t[lay][row][colS] = vals[j];
                }
            }
        }
    }
    // ---- biases in registers ----
    float bias1[NL][4], bias2s[4];
    #pragma unroll
    for (int lay = 0; lay < NL; ++lay)
        #pragma unroll
        for (int nt = 0; nt < 4; ++nt)
            bias1[lay][nt] = b1[lay * HID + nt * 16 + lr];
    #pragma unroll
    for (int nt = 0; nt < 4; ++nt)
        bias2s[nt] = b2[nt * 16 + lr] + b2[HID + nt * 16 + lr];
    __syncthreads();

    const float4* nfr = reinterpret_cast<const float4*>(nf);  // 16 float4 / row
    const float4* efr = reinterpret_cast<const float4*>(ef);  //  8 float4 / row

    // ---- prologue: idx for gen 0 and 1, features for gen 0 ----
    int g = blockIdx.x * WPB + w;
    int ev = 0, sv = 0, dv = 0;     // current gen
    int en = 0, sn = 0, dn = 0;     // next gen
    if (l < 32) {
        if (SORTED) { ev = esort[(size_t)g * 32 + l]; sv = ssort[(size_t)g * 32 + l];
                      dv = dsort[(size_t)g * 32 + l]; }
        else        { sv = src[(size_t)g * 32 + l];   dv = dst[(size_t)g * 32 + l]; }
    }
    {
        const int gn = g + TOTW;
        if (gn < NGRP && l < 32) {
            if (SORTED) { en = esort[(size_t)gn * 32 + l]; sn = ssort[(size_t)gn * 32 + l];
                          dn = dsort[(size_t)gn * 32 + l]; }
            else        { sn = src[(size_t)gn * 32 + l];   dn = dst[(size_t)gn * 32 + l]; }
        }
    }
    float4 nfv[2][4], efv[2][2];
    #pragma unroll
    for (int mt = 0; mt < 2; ++mt) {
        const int s = __shfl(sv, mt * 16 + lr);
        const float4* p = nfr + (size_t)s * 16;
        nfv[mt][0] = p[2 * lg];     nfv[mt][1] = p[2 * lg + 1];
        nfv[mt][2] = p[8 + 2 * lg]; nfv[mt][3] = p[9 + 2 * lg];
        const int e = SORTED ? __shfl(ev, mt * 16 + lr) : (g * 32 + mt * 16 + lr);
        const float4* q = efr + (size_t)e * 8;
        efv[mt][0] = q[2 * lg];
        efv[mt][1] = q[2 * lg + 1];
    }

    #pragma unroll 1
    while (g < NGRP) {
        const int gn  = g + TOTW;
        const int gnn = g + 2 * TOTW;
        const bool more = (gn < NGRP);

        // pack current group's A-fragments (consumes last iteration's loads)
        short8 cmbA[2][3];
        #pragma unroll
        for (int mt = 0; mt < 2; ++mt) {
            cmbA[mt][0] = pk8(nfv[mt][0], nfv[mt][1]);
            cmbA[mt][1] = pk8(nfv[mt][2], nfv[mt][3]);
            cmbA[mt][2] = pk8(efv[mt][0], efv[mt][1]);
        }

        // ---- issue ALL next-generation loads up front (hide under GEMMs) ----
        int en2 = 0, sn2 = 0, dn2 = 0;
        if (gnn < NGRP && l < 32) {
            if (SORTED) { en2 = esort[(size_t)gnn * 32 + l]; sn2 = ssort[(size_t)gnn * 32 + l];
                          dn2 = dsort[(size_t)gnn * 32 + l]; }
            else        { sn2 = src[(size_t)gnn * 32 + l];   dn2 = dst[(size_t)gnn * 32 + l]; }
        }
        float4 nfn[2][4], efn[2][2];
        if (more) {
            #pragma unroll
            for (int mt = 0; mt < 2; ++mt) {
                const int e = SORTED ? __shfl(en, mt * 16 + lr) : (gn * 32 + mt * 16 + lr);
                const float4* q = efr + (size_t)e * 8;
                efn[mt][0] = q[2 * lg];
                efn[mt][1] = q[2 * lg + 1];
                const int s = __shfl(sn, mt * 16 + lr);
                const float4* p = nfr + (size_t)s * 16;
                nfn[mt][0] = p[2 * lg];     nfn[mt][1] = p[2 * lg + 1];
                nfn[mt][2] = p[8 + 2 * lg]; nfn[mt][3] = p[9 + 2 * lg];
            }
        }

        f32x4 msg[2][4];
        #pragma unroll
        for (int nt = 0; nt < 4; ++nt) {
            const float v = bias2s[nt];
            msg[0][nt] = (f32x4){v, v, v, v};
            msg[1][nt] = (f32x4){v, v, v, v};
        }

        #pragma unroll
        for (int lay = 0; lay < NL; ++lay) {
            #pragma unroll
            for (int mt = 0; mt < 2; ++mt) {
                // ---- GEMM1(mt): h = relu(cmb @ W1 + b1), K=96 ----
                f32x4 acc[4];
                #pragma unroll
                for (int nt = 0; nt < 4; ++nt) {
                    const float bv = bias1[lay][nt];
                    acc[nt] = (f32x4){bv, bv, bv, bv};
                }
                __builtin_amdgcn_s_setprio(1);
                #pragma unroll
                for (int ks = 0; ks < 3; ++ks)
                    #pragma unroll
                    for (int nt = 0; nt < 4; ++nt) {
                        const short8 B = *reinterpret_cast<const short8*>(
                            &sW1t[lay][nt * 16 + lr][ks * 32 + 8 * lg]);
                        acc[nt] = __builtin_amdgcn_mfma_f32_16x16x32_bf16(
                            cmbA[mt][ks], B, acc[nt], 0, 0, 0);
                    }
                __builtin_amdgcn_s_setprio(0);
                // write h into sMS rows 0..15 (C layout: col=lane&15, row=(lane>>4)*4+reg)
                #pragma unroll
                for (int nt = 0; nt < 4; ++nt)
                    #pragma unroll
                    for (int r = 0; r < 4; ++r)
                        sMS[w][4 * lg + r][nt * 16 + lr] = bf16r(fmaxf(acc[nt][r], 0.0f));
                const short8 h0 = *reinterpret_cast<const short8*>(&sMS[w][lr][ 0 + 8 * lg]);
                const short8 h1 = *reinterpret_cast<const short8*>(&sMS[w][lr][32 + 8 * lg]);
                // ---- GEMM2(mt): msg += h @ W2, K=64 (swizzled B reads) ----
                __builtin_amdgcn_s_setprio(1);
                #pragma unroll
                for (int nt = 0; nt < 4; ++nt) {
                    const int cB = nt * 16 + lr;
                    const short8 B0 = *reinterpret_cast<const short8*>(
                        &sW2t[lay][cB][((0 + lg) ^ (lr & 7)) << 3]);
                    const short8 B1 = *reinterpret_cast<const short8*>(
                        &sW2t[lay][cB][((4 + lg) ^ (lr & 7)) << 3]);
                    msg[mt][nt] = __builtin_amdgcn_mfma_f32_16x16x32_bf16(h0, B0, msg[mt][nt], 0, 0, 0);
                    msg[mt][nt] = __builtin_amdgcn_mfma_f32_16x16x32_bf16(h1, B1, msg[mt][nt], 0, 0, 0);
                }
                __builtin_amdgcn_s_setprio(0);
            }
        }

        if (SORTED) {
            // ---- transpose messages into sMS rows 0..31 (bf16) ----
            #pragma unroll
            for (int mt = 0; mt < 2; ++mt)
                #pragma unroll
                for (int nt = 0; nt < 4; ++nt)
                    #pragma unroll
                    for (int r = 0; r < 4; ++r)
                        sMS[w][mt * 16 + 4 * lg + r][nt * 16 + lr] = bf16r(msg[mt][nt][r]);
            // ---- segmented reduction: dst-sorted rows -> ~3 atomics/group ----
            {
                float acc = 0.0f;
                #pragma unroll
                for (int r = 0; r < 32; ++r) {
                    acc += b2f((unsigned)sMS[w][r][l]);
                    const int dr = __shfl(dv, r);
                    const bool cut = (r == 31) || (dr != __shfl(dv, r + 1));
                    if (cut) {
                        atomicAdd(&agg[(size_t)dr * HID + l], acc);
                        acc = 0.0f;
                    }
                }
            }
        } else {
            #pragma unroll
            for (int mt = 0; mt < 2; ++mt)
                #pragma unroll
                for (int r = 0; r < 4; ++r) {
                    const int drow = __shfl(dv, mt * 16 + 4 * lg + r);
                    float* rowp = agg + (size_t)drow * HID;
                    #pragma unroll
                    for (int nt = 0; nt < 4; ++nt)
                        atomicAdd(rowp + nt * 16 + lr, msg[mt][nt][r]);
                }
            if (l < 32) atomicAdd(&deg[dv], 1.0f);
        }

        // rotate pipeline state
        ev = en; sv = sn; dv = dn;
        en = en2; sn = sn2; dn = dn2;
        #pragma unroll
        for (int mt = 0; mt < 2; ++mt) {
            #pragma unroll
            for (int i = 0; i < 4; ++i) nfv[mt][i] = nfn[mt][i];
            efv[mt][0] = efn[mt][0]; efv[mt][1] = efn[mt][1];
        }
        g = gn;
    }
}

// ============== node update (deg from CSR off), bf16 MFMA ===================
template <int USE_OFF>
__global__ __launch_bounds__(256, 2)
void node_update_kernel(const float* __restrict__ nf,
                        const float* __restrict__ agg,
                        const int* __restrict__ off,
                        const float* __restrict__ degf,
                        const float* __restrict__ uw1,
                        const float* __restrict__ ub1,
                        const float* __restrict__ uw2,
                        const float* __restrict__ ub2,
                        float* __restrict__ out)
{
    __shared__ __align__(16) ushort sAct[WPB][32][UPD_LD];
    __shared__ __align__(16) ushort sW1t[64][UPD_LD];
    __shared__ __align__(16) ushort sW2t[64][MSG_LD];
    __shared__ float sUB1[64], sUB2[64];

    const int tid = threadIdx.x;
    const int w  = tid >> 6;
    const int l  = tid & 63;
    const int lr = l & 15;
    const int lg = l >> 4;

    {   // weight stage
        const int k16 = tid >> 4, n0 = (tid & 15) * 4;
        #pragma unroll
        for (int it = 0; it < 8; ++it) {
            const int k = k16 + 16 * it;
            const float4 v = *reinterpret_cast<const float4*>(uw1 + (size_t)k * HID + n0);
            sW1t[n0 + 0][k] = bf16r(v.x);
            sW1t[n0 + 1][k] = bf16r(v.y);
            sW1t[n0 + 2][k] = bf16r(v.z);
            sW1t[n0 + 3][k] = bf16r(v.w);
        }
        #pragma unroll
        for (int it = 0; it < 4; ++it) {
            const int k = k16 + 16 * it;
            const float4 v = *reinterpret_cast<const float4*>(uw2 + (size_t)k * ND + n0);
            sW2t[n0 + 0][k] = bf16r(v.x);
            sW2t[n0 + 1][k] = bf16r(v.y);
            sW2t[n0 + 2][k] = bf16r(v.z);
            sW2t[n0 + 3][k] = bf16r(v.w);
        }
        if (tid < 64) { sUB1[tid] = ub1[tid]; sUB2[tid] = ub2[tid]; }
    }

    const int nbase = blockIdx.x * 128 + w * 32;
    float invv = 0.0f;
    if (l < 32) {
        const int n = min(nbase + l, NN - 1);
        const float d = USE_OFF ? (float)(off[n + 1] - off[n]) : degf[n];
        invv = 1.0f / (d + 1e-8f);
    }

    #pragma unroll
    for (int it = 0; it < 8; ++it) {
        const int row = lg + 4 * it;
        const int n = min(nbase + row, NN - 1);
        const float4 v = reinterpret_cast<const float4*>(nf + (size_t)n * ND)[lr];
        *reinterpret_cast<uint2*>(&sAct[w][row][lr * 4]) = pack4(v);
    }
    #pragma unroll
    for (int it = 0; it < 8; ++it) {
        const int row = lg + 4 * it;
        const int n = min(nbase + row, NN - 1);
        const float iv = __shfl(invv, row);
        float4 v = reinterpret_cast<const float4*>(agg + (size_t)n * HID)[lr];
        v.x *= iv; v.y *= iv; v.z *= iv; v.w *= iv;
        *reinterpret_cast<uint2*>(&sAct[w][row][ND + lr * 4]) = pack4(v);
    }
    __syncthreads();

    short8 A[2][4];
    #pragma unroll
    for (int mt = 0; mt < 2; ++mt)
        #pragma unroll
        for (int ks = 0; ks < 4; ++ks)
            A[mt][ks] = *reinterpret_cast<const short8*>(&sAct[w][mt * 16 + lr][ks * 32 + 8 * lg]);
    #pragma unroll
    for (int nt = 0; nt < 4; ++nt) {
        const int cB = nt * 16 + lr;
        short8 B[4];
        #pragma unroll
        for (int ks = 0; ks < 4; ++ks)
            B[ks] = *reinterpret_cast<const short8*>(&sW1t[cB][ks * 32 + 8 * lg]);
        const float bv = sUB1[cB];
        #pragma unroll
        for (int mt = 0; mt < 2; ++mt) {
            f32x4 acc = (f32x4){bv, bv, bv, bv};
            #pragma unroll
            for (int ks = 0; ks < 4; ++ks)
                acc = __builtin_amdgcn_mfma_f32_16x16x32_bf16(A[mt][ks], B[ks], acc, 0, 0, 0);
            const int rH = mt * 16 + 4 * lg;
            #pragma unroll
            for (int r = 0; r < 4; ++r)
                sAct[w][rH + r][cB] = bf16r(fmaxf(acc[r], 0.0f));
        }
    }

    f32x4 o[2][4];
    #pragma unroll
    for (int nt = 0; nt < 4; ++nt) {
        const float v = sUB2[nt * 16 + lr];
        o[0][nt] = (f32x4){v, v, v, v};
        o[1][nt] = (f32x4){v, v, v, v};
    }
    #pragma unroll
    for (int mt = 0; mt < 2; ++mt) {
        const short8 A0 = *reinterpret_cast<const short8*>(&sAct[w][mt * 16 + lr][ 0 + 8 * lg]);
        const short8 A1 = *reinterpret_cast<const short8*>(&sAct[w][mt * 16 + lr][32 + 8 * lg]);
        #pragma unroll
        for (int nt = 0; nt < 4; ++nt) {
            const int cB = nt * 16 + lr;
            const short8 B0 = *reinterpret_cast<const short8*>(&sW2t[cB][ 0 + 8 * lg]);
            const short8 B1 = *reinterpret_cast<const short8*>(&sW2t[cB][32 + 8 * lg]);
            o[mt][nt] = __builtin_amdgcn_mfma_f32_16x16x32_bf16(A0, B0, o[mt][nt], 0, 0, 0);
            o[mt][nt] = __builtin_amdgcn_mfma_f32_16x16x32_bf16(A1, B1, o[mt][nt], 0, 0, 0);
        }
    }

    #pragma unroll
    for (int mt = 0; mt < 2; ++mt)
        #pragma unroll
        for (int r = 0; r < 4; ++r) {
            const int n = nbase + mt * 16 + 4 * lg + r;
            if (n < NN) {
                float* rowp = out + (size_t)n * ND;
                #pragma unroll
                for (int nt = 0; nt < 4; ++nt)
                    rowp[nt * 16 + lr] = o[mt][nt][r];
            }
        }
}

extern "C" void kernel_launch(void* const* d_in, const int* in_sizes, int n_in,
                              void* d_out, int out_size, void* d_ws, size_t ws_size,
                              hipStream_t stream)
{
    const float* nf  = (const float*)d_in[0];
    const float* ef  = (const float*)d_in[1];
    const float* w1  = (const float*)d_in[2];
    const float* b1  = (const float*)d_in[3];
    const float* w2  = (const float*)d_in[4];
    const float* b2  = (const float*)d_in[5];
    const float* uw1 = (const float*)d_in[6];
    const float* ub1 = (const float*)d_in[7];
    const float* uw2 = (const float*)d_in[8];
    const float* ub2 = (const float*)d_in[9];
    const int*   src = (const int*)d_in[10];
    const int*   dst = (const int*)d_in[11];
    float* out = (float*)d_out;

    // ws layout (all 16B-aligned sizes)
    constexpr size_t ESB  = (size_t)NE * 4;            // esort
    constexpr size_t SSB  = (size_t)NE * 4;            // ssort
    constexpr size_t DSB  = (size_t)NE * 4;            // dsort
    constexpr size_t OFFB = (size_t)(NN + 1) * 4 + 12; // off, padded
    constexpr size_t CNTB = (size_t)NN * 4;            // cnt / cursor
    constexpr size_t BSUMB = 1024;
    constexpr size_t AGGB = (size_t)NN * HID * 4;      // 12.8 MB
    constexpr size_t NEED = ESB + SSB + DSB + OFFB + CNTB + BSUMB + AGGB;

    if (ws_size >= NEED) {
        char* p = (char*)d_ws;
        int* esort = (int*)p;              p += ESB;
        int* ssort = (int*)p;              p += SSB;
        int* dsort = (int*)p;              p += DSB;
        int* off   = (int*)p;              p += OFFB;
        int* cnt   = (int*)p;              p += CNTB;   // also cursor
        int* bsum  = (int*)p;              p += BSUMB;
        float* agg = (float*)p;

        (void)hipMemsetAsync(cnt, 0, CNTB, stream);
        (void)hipMemsetAsync(agg, 0, AGGB, stream);
        hist_kernel<<<NE / 256, 256, 0, stream>>>(dst, cnt);
        scanA_kernel<<<NB_SCAN, 256, 0, stream>>>(cnt, off, bsum);
        scanB_kernel<<<1, 256, 0, stream>>>(bsum);
        scanC_kernel<<<NB_SCAN, 256, 0, stream>>>(bsum, off, cnt);
        fill_kernel<<<NE / 256, 256, 0, stream>>>(src, dst, cnt, esort, ssort, dsort);
        msg_kernel<1><<<NBLK, 256, 0, stream>>>(nf, ef, w1, b1, w2, b2, src, dst,
                                                esort, ssort, dsort, agg, nullptr);
        node_update_kernel<1><<<(NN + 127) / 128, 256, 0, stream>>>(
            nf, agg, off, nullptr, uw1, ub1, uw2, ub2, out);
    } else {
        float* agg = (float*)d_ws;                    // [NN][HID]
        float* deg = agg + (size_t)NN * HID;          // [NN]
        (void)hipMemsetAsync(d_ws, 0, ((size_t)NN * HID + NN) * sizeof(float), stream);
        msg_kernel<0><<<NBLK, 256, 0, stream>>>(nf, ef, w1, b1, w2, b2, src, dst,
                                                nullptr, nullptr, nullptr, agg, deg);
        node_update_kernel<0><<<(NN + 127) / 128, 256, 0, stream>>>(
            nf, agg, nullptr, deg, uw1, ub1, uw2, ub2, out);
    }
}

// Round 11
// 203.075 us; speedup vs baseline: 2.4525x; 1.0285x over previous
//
#include <hip/hip_runtime.h>

#define NN 50000
#define NE 800000
#define ND 64
#define ED 32
#define HID 64
#define NL 2
#define IN_MSG 96   // ND + ED
#define IN_UPD 128  // ND + HID

#define W1_LD 104   // ushort stride for W1^T rows (96+8), 208B
#define MSG_LD 72   // ushort stride for msg/h scratch rows, 144B
#define UPD_LD 136  // ushort stride for node comb rows (128+8), 272B

#define NBLK 512            // 2 blocks/CU x 256 CUs
#define WPB 4
#define TOTW (NBLK * WPB)   // 2048 waves
#define NGRP (NE / 32)      // 25000 groups of 32 edges
#define NB_SCAN 196         // ceil(NN/256)

typedef __attribute__((ext_vector_type(8))) short short8;  // 8 bf16 = 4 VGPR
typedef __attribute__((ext_vector_type(4))) float f32x4;

__device__ inline ushort bf16r(float f) {  // fp32 -> bf16, RNE
    union { float f; unsigned u; } x; x.f = f;
    return (ushort)((x.u + 0x7FFFu + ((x.u >> 16) & 1u)) >> 16);
}
__device__ inline float b2f(unsigned u) {
    union { unsigned u; float f; } x; x.u = u << 16; return x.f;
}
__device__ inline short8 pk8(float4 a, float4 b) {
    short8 r;
    r[0] = (short)bf16r(a.x); r[1] = (short)bf16r(a.y);
    r[2] = (short)bf16r(a.z); r[3] = (short)bf16r(a.w);
    r[4] = (short)bf16r(b.x); r[5] = (short)bf16r(b.y);
    r[6] = (short)bf16r(b.z); r[7] = (short)bf16r(b.w);
    return r;
}
__device__ inline uint2 pack4(float4 v) {
    return make_uint2((unsigned)bf16r(v.x) | ((unsigned)bf16r(v.y) << 16),
                      (unsigned)bf16r(v.z) | ((unsigned)bf16r(v.w) << 16));
}
__device__ inline uint2 pkacc(f32x4 a) {   // 4 f32 -> 4 bf16 (relu'd outside)
    return make_uint2((unsigned)bf16r(a[0]) | ((unsigned)bf16r(a[1]) << 16),
                      (unsigned)bf16r(a[2]) | ((unsigned)bf16r(a[3]) << 16));
}

// ============================ dst-CSR build =================================
__global__ __launch_bounds__(256) void hist_kernel(const int* __restrict__ dst,
                                                   int* __restrict__ cnt)
{
    const int i = blockIdx.x * 256 + threadIdx.x;   // grid exact
    atomicAdd(&cnt[dst[i]], 1);
}

__global__ __launch_bounds__(256) void scanA_kernel(const int* __restrict__ cnt,
                                                    int* __restrict__ off,
                                                    int* __restrict__ bsum)
{
    __shared__ int buf[256];
    const int t = threadIdx.x;
    const int i = blockIdx.x * 256 + t;
    const int v = (i < NN) ? cnt[i] : 0;
    buf[t] = v;
    __syncthreads();
    #pragma unroll
    for (int d = 1; d < 256; d <<= 1) {
        const int x = (t >= d) ? buf[t - d] : 0;
        __syncthreads();
        buf[t] += x;
        __syncthreads();
    }
    if (i < NN) off[i] = buf[t] - v;
    if (t == 255) bsum[blockIdx.x] = buf[255];
}

__global__ __launch_bounds__(256) void scanB_kernel(int* __restrict__ bsum)
{
    __shared__ int buf[256];
    const int t = threadIdx.x;
    buf[t] = (t < NB_SCAN) ? bsum[t] : 0;
    __syncthreads();
    #pragma unroll
    for (int d = 1; d < 256; d <<= 1) {
        const int x = (t >= d) ? buf[t - d] : 0;
        __syncthreads();
        buf[t] += x;
        __syncthreads();
    }
    if (t < NB_SCAN) bsum[t] = buf[t];
}

__global__ __launch_bounds__(256) void scanC_kernel(const int* __restrict__ bsum,
                                                    int* __restrict__ off,
                                                    int* __restrict__ cursor)
{
    const int b = blockIdx.x;
    const int i = b * 256 + threadIdx.x;
    const int boff = (b > 0) ? bsum[b - 1] : 0;
    if (i < NN) {
        const int e = off[i] + boff;
        off[i] = e;
        cursor[i] = e;
    }
    if (i == 0) off[NN] = NE;
}

// scatter into dst-sorted order: one int4 (edge, src, dst, 0) per edge
__global__ __launch_bounds__(256) void fill_kernel(const int* __restrict__ src,
                                                   const int* __restrict__ dst,
                                                   int* __restrict__ cursor,
                                                   int4* __restrict__ esd)
{
    const int i = blockIdx.x * 256 + threadIdx.x;   // grid exact
    const int d = dst[i];
    const int pos = atomicAdd(&cursor[d], 1);
    esd[pos] = make_int4(i, src[i], d, 0);
}

// ======================= edge message MLP (MFMA) ============================
// Swapped MFMA operands: mfma(W_frag, x_frag) so each lane holds 4 consecutive
// output features per accumulator reg -> packed b64 LDS writes.
// SORTED=1: dst-sorted edges, segmented reduce -> ~3 row-atomics/group.
// SORTED=0: fallback, per-row atomics + deg.
template <int SORTED>
__global__ __launch_bounds__(256, 2)
void msg_kernel(const float* __restrict__ nf,
                const float* __restrict__ ef,
                const float* __restrict__ w1,
                const float* __restrict__ b1,
                const float* __restrict__ w2,
                const float* __restrict__ b2,
                const int* __restrict__ src,
                const int* __restrict__ dst,
                const int4* __restrict__ esd,
                float* __restrict__ agg,
                float* __restrict__ deg)
{
    __shared__ __align__(16) ushort sW1t[NL][64][W1_LD];  // 26,624 B
    __shared__ __align__(16) ushort sMS[WPB][32][MSG_LD]; // 18,432 B (h / msg scratch)
    __shared__ __align__(16) float sB1f[NL][64];          //    512 B
    __shared__ __align__(16) float sB2f[64];              //    256 B  => ~45.8 KB

    const int tid = threadIdx.x;
    const int w  = tid >> 6;
    const int l  = tid & 63;
    const int lr = l & 15;
    const int lg = l >> 4;

    // ---- one-time stage: W1^T (padded) + biases ----
    {
        const int k16 = tid >> 4, n0 = (tid & 15) * 4;
        #pragma unroll
        for (int lay = 0; lay < NL; ++lay)
            #pragma unroll
            for (int it = 0; it < 6; ++it) {
                const int k = k16 + 16 * it;   // 0..95
                const float4 v = *reinterpret_cast<const float4*>(
                    w1 + ((size_t)lay * IN_MSG + k) * HID + n0);
                sW1t[lay][n0 + 0][k] = bf16r(v.x);
                sW1t[lay][n0 + 1][k] = bf16r(v.y);
                sW1t[lay][n0 + 2][k] = bf16r(v.z);
                sW1t[lay][n0 + 3][k] = bf16r(v.w);
            }
        if (tid < NL * 64) sB1f[tid >> 6][tid & 63] = b1[tid];
        if (tid < 64) sB2f[tid] = b2[tid] + b2[HID + tid];
    }
    // ---- W2 fragments in registers (both layers): lane holds W2[k][j] ----
    short8 w2f[NL][4][2];
    #pragma unroll
    for (int lay = 0; lay < NL; ++lay)
        #pragma unroll
        for (int nt = 0; nt < 4; ++nt)
            #pragma unroll
            for (int ks = 0; ks < 2; ++ks) {
                short8 t;
                #pragma unroll
                for (int j = 0; j < 8; ++j)
                    t[j] = (short)bf16r(
                        w2[((size_t)lay * HID + ks * 32 + 8 * lg + j) * HID + nt * 16 + lr]);
                w2f[lay][nt][ks] = t;
            }
    __syncthreads();

    const float4* nfr = reinterpret_cast<const float4*>(nf);  // 16 float4 / row
    const float4* efr = reinterpret_cast<const float4*>(ef);  //  8 float4 / row

    // ---- prologue: idx gen 0 and 1, features gen 0 ----
    int g = blockIdx.x * WPB + w;
    int ev = 0, sv = 0, dv = 0;
    int en = 0, sn = 0, dn = 0;
    if (l < 32) {
        if (SORTED) { const int4 t = esd[(size_t)g * 32 + l]; ev = t.x; sv = t.y; dv = t.z; }
        else        { sv = src[(size_t)g * 32 + l]; dv = dst[(size_t)g * 32 + l]; }
    }
    {
        const int gn = g + TOTW;
        if (gn < NGRP && l < 32) {
            if (SORTED) { const int4 t = esd[(size_t)gn * 32 + l]; en = t.x; sn = t.y; dn = t.z; }
            else        { sn = src[(size_t)gn * 32 + l]; dn = dst[(size_t)gn * 32 + l]; }
        }
    }
    float4 nfv[2][4], efv[2][2];
    #pragma unroll
    for (int mt = 0; mt < 2; ++mt) {
        const int s = __shfl(sv, mt * 16 + lr);
        const float4* p = nfr + (size_t)s * 16;
        nfv[mt][0] = p[2 * lg];     nfv[mt][1] = p[2 * lg + 1];
        nfv[mt][2] = p[8 + 2 * lg]; nfv[mt][3] = p[9 + 2 * lg];
        const int e = SORTED ? __shfl(ev, mt * 16 + lr) : (g * 32 + mt * 16 + lr);
        const float4* q = efr + (size_t)e * 8;
        efv[mt][0] = q[2 * lg];
        efv[mt][1] = q[2 * lg + 1];
    }

    #pragma unroll 1
    while (g < NGRP) {
        const int gn  = g + TOTW;
        const int gnn = g + 2 * TOTW;
        const bool more = (gn < NGRP);

        // pack current A(B)-fragments
        short8 cmbA[2][3];
        #pragma unroll
        for (int mt = 0; mt < 2; ++mt) {
            cmbA[mt][0] = pk8(nfv[mt][0], nfv[mt][1]);
            cmbA[mt][1] = pk8(nfv[mt][2], nfv[mt][3]);
            cmbA[mt][2] = pk8(efv[mt][0], efv[mt][1]);
        }

        // issue all next-generation loads up front
        int en2 = 0, sn2 = 0, dn2 = 0;
        if (gnn < NGRP && l < 32) {
            if (SORTED) { const int4 t = esd[(size_t)gnn * 32 + l]; en2 = t.x; sn2 = t.y; dn2 = t.z; }
            else        { sn2 = src[(size_t)gnn * 32 + l]; dn2 = dst[(size_t)gnn * 32 + l]; }
        }
        float4 nfn[2][4], efn[2][2];
        if (more) {
            #pragma unroll
            for (int mt = 0; mt < 2; ++mt) {
                const int e = SORTED ? __shfl(en, mt * 16 + lr) : (gn * 32 + mt * 16 + lr);
                const float4* q = efr + (size_t)e * 8;
                efn[mt][0] = q[2 * lg];
                efn[mt][1] = q[2 * lg + 1];
                const int s = __shfl(sn, mt * 16 + lr);
                const float4* p = nfr + (size_t)s * 16;
                nfn[mt][0] = p[2 * lg];     nfn[mt][1] = p[2 * lg + 1];
                nfn[mt][2] = p[8 + 2 * lg]; nfn[mt][3] = p[9 + 2 * lg];
            }
        }

        // msg[mt][nt]: lane holds msg[edge=mt*16+lr][j = nt*16+4*lg+reg]
        f32x4 msg[2][4];
        #pragma unroll
        for (int nt = 0; nt < 4; ++nt) {
            const f32x4 b2v = *reinterpret_cast<const f32x4*>(&sB2f[nt * 16 + 4 * lg]);
            msg[0][nt] = b2v;
            msg[1][nt] = b2v;
        }

        #pragma unroll
        for (int lay = 0; lay < NL; ++lay) {
            // ---- GEMM1 (swapped): acc[mt][nt] = W1t-frag x cmbA[mt], K=96 ----
            f32x4 acc[2][4];
            #pragma unroll
            for (int nt = 0; nt < 4; ++nt) {
                const f32x4 bv = *reinterpret_cast<const f32x4*>(&sB1f[lay][nt * 16 + 4 * lg]);
                acc[0][nt] = bv;
                acc[1][nt] = bv;
            }
            __builtin_amdgcn_s_setprio(1);
            #pragma unroll
            for (int ks = 0; ks < 3; ++ks)
                #pragma unroll
                for (int nt = 0; nt < 4; ++nt) {
                    const short8 Bw = *reinterpret_cast<const short8*>(
                        &sW1t[lay][nt * 16 + lr][ks * 32 + 8 * lg]);
                    acc[0][nt] = __builtin_amdgcn_mfma_f32_16x16x32_bf16(Bw, cmbA[0][ks], acc[0][nt], 0, 0, 0);
                    acc[1][nt] = __builtin_amdgcn_mfma_f32_16x16x32_bf16(Bw, cmbA[1][ks], acc[1][nt], 0, 0, 0);
                }
            __builtin_amdgcn_s_setprio(0);
            // ---- h = relu(acc): packed b64 writes; row=edge, col=4 features ----
            #pragma unroll
            for (int mt = 0; mt < 2; ++mt)
                #pragma unroll
                for (int nt = 0; nt < 4; ++nt) {
                    f32x4 a = acc[mt][nt];
                    a[0] = fmaxf(a[0], 0.0f); a[1] = fmaxf(a[1], 0.0f);
                    a[2] = fmaxf(a[2], 0.0f); a[3] = fmaxf(a[3], 0.0f);
                    *reinterpret_cast<uint2*>(&sMS[w][mt * 16 + lr][nt * 16 + 4 * lg]) = pkacc(a);
                }
            // ---- h B-fragments: row=edge, k-slice = 8*lg ----
            short8 hA[2][2];
            #pragma unroll
            for (int mt = 0; mt < 2; ++mt)
                #pragma unroll
                for (int ks = 0; ks < 2; ++ks)
                    hA[mt][ks] = *reinterpret_cast<const short8*>(
                        &sMS[w][mt * 16 + lr][ks * 32 + 8 * lg]);
            // ---- GEMM2 (swapped): msg += W2-frag x h, K=64 ----
            __builtin_amdgcn_s_setprio(1);
            #pragma unroll
            for (int ks = 0; ks < 2; ++ks)
                #pragma unroll
                for (int nt = 0; nt < 4; ++nt) {
                    msg[0][nt] = __builtin_amdgcn_mfma_f32_16x16x32_bf16(w2f[lay][nt][ks], hA[0][ks], msg[0][nt], 0, 0, 0);
                    msg[1][nt] = __builtin_amdgcn_mfma_f32_16x16x32_bf16(w2f[lay][nt][ks], hA[1][ks], msg[1][nt], 0, 0, 0);
                }
            __builtin_amdgcn_s_setprio(0);
        }

        // ---- msg -> LDS rows (packed b64), row=edge, then reduce ----
        #pragma unroll
        for (int mt = 0; mt < 2; ++mt)
            #pragma unroll
            for (int nt = 0; nt < 4; ++nt)
                *reinterpret_cast<uint2*>(&sMS[w][mt * 16 + lr][nt * 16 + 4 * lg]) = pkacc(msg[mt][nt]);

        if (SORTED) {
            // segmented reduction over dst-sorted rows; readlane -> uniform cut
            float acc = 0.0f;
            int dr = __builtin_amdgcn_readlane(dv, 0);
            #pragma unroll
            for (int r = 0; r < 32; ++r) {
                acc += b2f((unsigned)sMS[w][r][l]);
                const int drn = (r < 31) ? __builtin_amdgcn_readlane(dv, r + 1) : -1;
                if (r == 31 || dr != drn) {
                    atomicAdd(&agg[(size_t)dr * HID + l], acc);
                    acc = 0.0f;
                }
                dr = drn;
            }
        } else {
            #pragma unroll
            for (int r = 0; r < 32; ++r) {
                const int dr = __builtin_amdgcn_readlane(dv, r);
                atomicAdd(&agg[(size_t)dr * HID + l], b2f((unsigned)sMS[w][r][l]));
            }
            if (l < 32) atomicAdd(&deg[dv], 1.0f);
        }

        // rotate pipeline state
        ev = en; sv = sn; dv = dn;
        en = en2; sn = sn2; dn = dn2;
        #pragma unroll
        for (int mt = 0; mt < 2; ++mt) {
            #pragma unroll
            for (int i = 0; i < 4; ++i) nfv[mt][i] = nfn[mt][i];
            efv[mt][0] = efn[mt][0]; efv[mt][1] = efn[mt][1];
        }
        g = gn;
    }
}

// ============== node update (deg from CSR off), bf16 MFMA ===================
template <int USE_OFF>
__global__ __launch_bounds__(256, 2)
void node_update_kernel(const float* __restrict__ nf,
                        const float* __restrict__ agg,
                        const int* __restrict__ off,
                        const float* __restrict__ degf,
                        const float* __restrict__ uw1,
                        const float* __restrict__ ub1,
                        const float* __restrict__ uw2,
                        const float* __restrict__ ub2,
                        float* __restrict__ out)
{
    __shared__ __align__(16) ushort sAct[WPB][32][UPD_LD];
    __shared__ __align__(16) ushort sW1t[64][UPD_LD];
    __shared__ __align__(16) ushort sW2t[64][MSG_LD];
    __shared__ float sUB1[64], sUB2[64];

    const int tid = threadIdx.x;
    const int w  = tid >> 6;
    const int l  = tid & 63;
    const int lr = l & 15;
    const int lg = l >> 4;

    {   // weight stage
        const int k16 = tid >> 4, n0 = (tid & 15) * 4;
        #pragma unroll
        for (int it = 0; it < 8; ++it) {
            const int k = k16 + 16 * it;
            const float4 v = *reinterpret_cast<const float4*>(uw1 + (size_t)k * HID + n0);
            sW1t[n0 + 0][k] = bf16r(v.x);
            sW1t[n0 + 1][k] = bf16r(v.y);
            sW1t[n0 + 2][k] = bf16r(v.z);
            sW1t[n0 + 3][k] = bf16r(v.w);
        }
        #pragma unroll
        for (int it = 0; it < 4; ++it) {
            const int k = k16 + 16 * it;
            const float4 v = *reinterpret_cast<const float4*>(uw2 + (size_t)k * ND + n0);
            sW2t[n0 + 0][k] = bf16r(v.x);
            sW2t[n0 + 1][k] = bf16r(v.y);
            sW2t[n0 + 2][k] = bf16r(v.z);
            sW2t[n0 + 3][k] = bf16r(v.w);
        }
        if (tid < 64) { sUB1[tid] = ub1[tid]; sUB2[tid] = ub2[tid]; }
    }

    const int nbase = blockIdx.x * 128 + w * 32;
    float invv = 0.0f;
    if (l < 32) {
        const int n = min(nbase + l, NN - 1);
        const float d = USE_OFF ? (float)(off[n + 1] - off[n]) : degf[n];
        invv = 1.0f / (d + 1e-8f);
    }

    #pragma unroll
    for (int it = 0; it < 8; ++it) {
        const int row = lg + 4 * it;
        const int n = min(nbase + row, NN - 1);
        const float4 v = reinterpret_cast<const float4*>(nf + (size_t)n * ND)[lr];
        *reinterpret_cast<uint2*>(&sAct[w][row][lr * 4]) = pack4(v);
    }
    #pragma unroll
    for (int it = 0; it < 8; ++it) {
        const int row = lg + 4 * it;
        const int n = min(nbase + row, NN - 1);
        const float iv = __shfl(invv, row);
        float4 v = reinterpret_cast<const float4*>(agg + (size_t)n * HID)[lr];
        v.x *= iv; v.y *= iv; v.z *= iv; v.w *= iv;
        *reinterpret_cast<uint2*>(&sAct[w][row][ND + lr * 4]) = pack4(v);
    }
    __syncthreads();

    short8 A[2][4];
    #pragma unroll
    for (int mt = 0; mt < 2; ++mt)
        #pragma unroll
        for (int ks = 0; ks < 4; ++ks)
            A[mt][ks] = *reinterpret_cast<const short8*>(&sAct[w][mt * 16 + lr][ks * 32 + 8 * lg]);
    #pragma unroll
    for (int nt = 0; nt < 4; ++nt) {
        const int cB = nt * 16 + lr;
        short8 B[4];
        #pragma unroll
        for (int ks = 0; ks < 4; ++ks)
            B[ks] = *reinterpret_cast<const short8*>(&sW1t[cB][ks * 32 + 8 * lg]);
        const float bv = sUB1[cB];
        #pragma unroll
        for (int mt = 0; mt < 2; ++mt) {
            f32x4 acc = (f32x4){bv, bv, bv, bv};
            #pragma unroll
            for (int ks = 0; ks < 4; ++ks)
                acc = __builtin_amdgcn_mfma_f32_16x16x32_bf16(A[mt][ks], B[ks], acc, 0, 0, 0);
            const int rH = mt * 16 + 4 * lg;
            #pragma unroll
            for (int r = 0; r < 4; ++r)
                sAct[w][rH + r][cB] = bf16r(fmaxf(acc[r], 0.0f));
        }
    }

    f32x4 o[2][4];
    #pragma unroll
    for (int nt = 0; nt < 4; ++nt) {
        const float v = sUB2[nt * 16 + lr];
        o[0][nt] = (f32x4){v, v, v, v};
        o[1][nt] = (f32x4){v, v, v, v};
    }
    #pragma unroll
    for (int mt = 0; mt < 2; ++mt) {
        const short8 A0 = *reinterpret_cast<const short8*>(&sAct[w][mt * 16 + lr][ 0 + 8 * lg]);
        const short8 A1 = *reinterpret_cast<const short8*>(&sAct[w][mt * 16 + lr][32 + 8 * lg]);
        #pragma unroll
        for (int nt = 0; nt < 4; ++nt) {
            const int cB = nt * 16 + lr;
            const short8 B0 = *reinterpret_cast<const short8*>(&sW2t[cB][ 0 + 8 * lg]);
            const short8 B1 = *reinterpret_cast<const short8*>(&sW2t[cB][32 + 8 * lg]);
            o[mt][nt] = __builtin_amdgcn_mfma_f32_16x16x32_bf16(A0, B0, o[mt][nt], 0, 0, 0);
            o[mt][nt] = __builtin_amdgcn_mfma_f32_16x16x32_bf16(A1, B1, o[mt][nt], 0, 0, 0);
        }
    }

    #pragma unroll
    for (int mt = 0; mt < 2; ++mt)
        #pragma unroll
        for (int r = 0; r < 4; ++r) {
            const int n = nbase + mt * 16 + 4 * lg + r;
            if (n < NN) {
                float* rowp = out + (size_t)n * ND;
                #pragma unroll
                for (int nt = 0; nt < 4; ++nt)
                    rowp[nt * 16 + lr] = o[mt][nt][r];
            }
        }
}

extern "C" void kernel_launch(void* const* d_in, const int* in_sizes, int n_in,
                              void* d_out, int out_size, void* d_ws, size_t ws_size,
                              hipStream_t stream)
{
    const float* nf  = (const float*)d_in[0];
    const float* ef  = (const float*)d_in[1];
    const float* w1  = (const float*)d_in[2];
    const float* b1  = (const float*)d_in[3];
    const float* w2  = (const float*)d_in[4];
    const float* b2  = (const float*)d_in[5];
    const float* uw1 = (const float*)d_in[6];
    const float* ub1 = (const float*)d_in[7];
    const float* uw2 = (const float*)d_in[8];
    const float* ub2 = (const float*)d_in[9];
    const int*   src = (const int*)d_in[10];
    const int*   dst = (const int*)d_in[11];
    float* out = (float*)d_out;

    constexpr size_t ESDB = (size_t)NE * 16;           // 12.8 MB (int4 per edge)
    constexpr size_t OFFB = (size_t)(NN + 1) * 4 + 12;
    constexpr size_t CNTB = (size_t)NN * 4;
    constexpr size_t BSUMB = 1024;
    constexpr size_t AGGB = (size_t)NN * HID * 4;      // 12.8 MB
    constexpr size_t NEED = ESDB + OFFB + CNTB + BSUMB + AGGB;

    if (ws_size >= NEED) {
        char* p = (char*)d_ws;
        int4* esd  = (int4*)p;             p += ESDB;
        int*  off  = (int*)p;              p += OFFB;
        int*  cnt  = (int*)p;              p += CNTB;   // also cursor
        int*  bsum = (int*)p;              p += BSUMB;
        float* agg = (float*)p;

        (void)hipMemsetAsync(cnt, 0, CNTB, stream);
        (void)hipMemsetAsync(agg, 0, AGGB, stream);
        hist_kernel<<<NE / 256, 256, 0, stream>>>(dst, cnt);
        scanA_kernel<<<NB_SCAN, 256, 0, stream>>>(cnt, off, bsum);
        scanB_kernel<<<1, 256, 0, stream>>>(bsum);
        scanC_kernel<<<NB_SCAN, 256, 0, stream>>>(bsum, off, cnt);
        fill_kernel<<<NE / 256, 256, 0, stream>>>(src, dst, cnt, esd);
        msg_kernel<1><<<NBLK, 256, 0, stream>>>(nf, ef, w1, b1, w2, b2, src, dst,
                                                esd, agg, nullptr);
        node_update_kernel<1><<<(NN + 127) / 128, 256, 0, stream>>>(
            nf, agg, off, nullptr, uw1, ub1, uw2, ub2, out);
    } else {
        float* agg = (float*)d_ws;                    // [NN][HID]
        float* deg = agg + (size_t)NN * HID;          // [NN]
        (void)hipMemsetAsync(d_ws, 0, ((size_t)NN * HID + NN) * sizeof(float), stream);
        msg_kernel<0><<<NBLK, 256, 0, stream>>>(nf, ef, w1, b1, w2, b2, src, dst,
                                                nullptr, agg, deg);
        node_update_kernel<0><<<(NN + 127) / 128, 256, 0, stream>>>(
            nf, agg, nullptr, deg, uw1, ub1, uw2, ub2, out);
    }
}